// Round 13
// baseline (221.526 us; speedup 1.0000x reference)
//
#include <hip/hip_runtime.h>

// ODENet forward, round 13: r12 (persistent WGs, grid 256, 4 tiles/WG,
// weights loaded once, dedicated LDS regions) + de-conflicted epilogue.
// Evidence: SQ_LDS_BANK_CONFLICT bit-identical 1.312e7 across r6-r12 at
// wildly different eval counts -> all conflicts are in the per-tile fixed
// sections; dominant source was yfin row stride 128 (== 0 mod 32 banks: all
// 64 lanes on one bank per k). Fix: stride 132 + float4 stores/reads.
// Core (validated): pack kernel + no-spill 128-VGPR weight residency, f16
// MFMA 16x16x32, fp32 state, RK4 N=1 (absmax bit-identical 0.03125 at
// N=8/6/4/3/2/1), lo/hi b64 conflict-free LDS B-fragments, ping-pong 2x32KB.
// HISTORY (do not regress): r5 launch_bounds(512,4) -> weight spill (3.3GB
// HBM); r8 inline f32 gather -> ~50-reg spill (WRITE 105MB); r11 LDS union
// overlays across tile loop -> post-timing divergence (keep dedicated
// regions). Keep launch_bounds(512,2).

typedef _Float16 half8 __attribute__((ext_vector_type(8)));
typedef _Float16 half4 __attribute__((ext_vector_type(4)));
typedef float    floatx4 __attribute__((ext_vector_type(4)));

#define MFMA16 __builtin_amdgcn_mfma_f32_16x16x32_f16

constexpr int DDIM  = 118;
constexpr int NSTEP = 1;
constexpr int TILES = 4;      // row-tiles of 64 per WG (grid 256)
constexpr int YLD   = 132;    // yfin row stride (floats): 132%8==4 -> banks spread

// B-frag element group offset (f16 units) inside one 32KB half-buffer:
// element(k = 32*kc + 8*(slot>>4) + 4*h + t, n = 16*nb + (slot&15)) at
// IDX(kc,nb,h,slot) + t.
__device__ __forceinline__ int IDX(int kc, int nb, int h, int slot) {
  return (((kc*4 + nb)*2 + h)*64 + slot)*4;
}

struct SMemT {
  _Float16 b[2][16384];   // ping-pong activation buffers, 32KB each
  float raw[7552];        // x staging (dedicated, 30208B)
  float yfin[64 * YLD];   // epilogue 64 x 128 padded to 132 (33792B)
};                        // total 130048 B < 160KB/CU

// Fused pack: fp32 W[K][N] (k-major) -> A-fragment order f16 for all 3 mats.
// A1: 16mb x 4kc at out[0..32767]; A2: 16mb x 8kc at +32768; A3: 8mb x 8kc at +98304.
__global__ void pack_weights_all(const float* __restrict__ W1,
                                 const float* __restrict__ W2,
                                 const float* __restrict__ W3,
                                 _Float16* __restrict__ out)
{
  int idx = blockIdx.x * 256 + threadIdx.x;     // 0 .. 131071
  const float* W; int N, kcBits, base;
  if (idx < 32768)        { W = W1; N = 256; kcBits = 2; base = 0;     }
  else if (idx < 98304)   { W = W2; N = 256; kcBits = 3; base = 32768; }
  else                    { W = W3; N = 128; kcBits = 3; base = 98304; }
  int rel = idx - base;
  int j  = rel & 7;
  int L  = (rel >> 3) & 63;
  int blk = rel >> 9;
  int kc = blk & ((1 << kcBits) - 1);
  int mb = blk >> kcBits;
  int k = 32*kc + 8*(L >> 4) + j;
  int m = 16*mb + (L & 15);
  out[idx] = (_Float16)W[k*N + m];
}

__device__ __forceinline__ half8 join(half4 lo, half4 hi) {
  return __builtin_shufflevector(lo, hi, 0, 1, 2, 3, 4, 5, 6, 7);
}

__global__ __launch_bounds__(512, 2)
void ode_kernel(const float* __restrict__ x,
                const float* __restrict__ b1v, const float* __restrict__ b2v,
                const float* __restrict__ b3v,
                const float* __restrict__ Wl,  const float* __restrict__ bl,
                const _Float16* __restrict__ Aw, float* __restrict__ out)
{
  __shared__ SMemT sm;
  const int tid = threadIdx.x;
  const int w   = tid >> 6;    // wave 0..7
  const int l   = tid & 63;
  const int q   = l >> 4;
  const int c   = l & 15;

  const int sh  = q & 1;       // store-side h
  const int qh  = q >> 1;

  // ---- weight A-fragments -> registers (ONCE per WG): 128 VGPRs/wave ----
  const _Float16* A1 = Aw;           // 16 mb x 4 kc
  const _Float16* A2 = Aw + 32768;   // 16 mb x 8 kc
  const _Float16* A3 = Aw + 98304;   //  8 mb x 8 kc
  half8 WA1[2][4], WA2[2][8], WA3[8];
#pragma unroll
  for (int i = 0; i < 2; ++i)
#pragma unroll
    for (int kc = 0; kc < 4; ++kc)
      WA1[i][kc] = *(const half8*)&A1[((((2*w+i)*4 + kc)*64) + l)*8];
#pragma unroll
  for (int i = 0; i < 2; ++i)
#pragma unroll
    for (int kc = 0; kc < 8; ++kc)
      WA2[i][kc] = *(const half8*)&A2[((((2*w+i)*8 + kc)*64) + l)*8];
#pragma unroll
  for (int kc = 0; kc < 8; ++kc)
    WA3[kc] = *(const half8*)&A3[(((w*8 + kc)*64) + l)*8];

  // ---- biases (per-lane; m = 16*mb + 4q + r), once per WG ----
  float bs1[2][4], bs2[2][4], bs3[4];
#pragma unroll
  for (int i = 0; i < 2; ++i)
#pragma unroll
    for (int r = 0; r < 4; ++r) {
      bs1[i][r] = b1v[16*(2*w+i) + 4*q + r];
      bs2[i][r] = b2v[16*(2*w+i) + 4*q + r];
    }
#pragma unroll
  for (int r = 0; r < 4; ++r) bs3[r] = b3v[16*w + 4*q + r];

  const float h = 1.0f / (float)NSTEP;

#pragma unroll 1
  for (int t = 0; t < TILES; ++t) {
    const int R = blockIdx.x * (64 * TILES) + t * 64;

    // ---- stage this tile's x block into dedicated raw ----
    const float* xblk = x + (size_t)R * DDIM;
    for (int i = tid; i < 1888; i += 512)
      *(float4*)&sm.raw[i*4] = *(const float4*)&xblk[i*4];
    __syncthreads();   // raw ready

    // ---- build initial S in b[0] (lo/hi B-frag layout, zero-pad k>=118) --
    for (int g = tid; g < 2048; g += 512) {
      int slot = g & 63;
      int hh   = (g >> 6) & 1;
      int nb   = (g >> 7) & 3;
      int kc   = g >> 9;
      int n  = 16*nb + (slot & 15);
      int k0 = 32*kc + 8*(slot >> 4) + 4*hh;
      half4 v;
#pragma unroll
      for (int tt = 0; tt < 4; ++tt) {
        int k = k0 + tt;
        v[tt] = (_Float16)((k < DDIM) ? sm.raw[n*DDIM + k] : 0.0f);
      }
      *(half4*)&sm.b[0][IDX(kc, nb, hh, slot)] = v;
    }

    // ---- Y init (fp32): d = 16w + 4q + r, n = 16nb + c ----
    float Y[4][4], ACC[4][4];
#pragma unroll
    for (int nb = 0; nb < 4; ++nb)
#pragma unroll
      for (int r = 0; r < 4; ++r) {
        int d = 16*w + 4*q + r;
        int n = 16*nb + c;
        Y[nb][r]  = (d < DDIM) ? sm.raw[n*DDIM + d] : 0.0f;
        ACC[nb][r] = 0.0f;
      }
    __syncthreads();   // S ready

#pragma unroll 1
    for (int it = 0; it < 4*NSTEP; ++it) {
      const int s4 = it & 3;
      _Float16* P = sm.b[it & 1];         // holds S, receives H2
      _Float16* Q = sm.b[(it & 1) ^ 1];   // receives H1, then S'

      // ---- layer 1: C1[i][nb], kc<4 (reads S from P) ----
      {
        floatx4 C1[2][4];
#pragma unroll
        for (int i = 0; i < 2; ++i)
#pragma unroll
          for (int nb = 0; nb < 4; ++nb)
#pragma unroll
            for (int r = 0; r < 4; ++r) C1[i][nb][r] = bs1[i][r];
#pragma unroll
        for (int kc = 0; kc < 4; ++kc) {
          half8 bf[4];
#pragma unroll
          for (int nb = 0; nb < 4; ++nb) {
            half4 lo = *(const half4*)&P[IDX(kc, nb, 0, l)];
            half4 hi = *(const half4*)&P[IDX(kc, nb, 1, l)];
            bf[nb] = join(lo, hi);
          }
#pragma unroll
          for (int i = 0; i < 2; ++i)
#pragma unroll
            for (int nb = 0; nb < 4; ++nb)
              C1[i][nb] = MFMA16(WA1[i][kc], bf[nb], C1[i][nb], 0, 0, 0);
        }
        // store H1 -> Q: mb = 2w+i -> kc_t = w, sq = 2i + qh, h = sh
#pragma unroll
        for (int i = 0; i < 2; ++i) {
          const int sq = 2*i + qh;
#pragma unroll
          for (int nb = 0; nb < 4; ++nb) {
            half4 v;
#pragma unroll
            for (int r = 0; r < 4; ++r) v[r] = (_Float16)fmaxf(C1[i][nb][r], 0.0f);
            *(half4*)&Q[IDX(w, nb, sh, 16*sq + c)] = v;
          }
        }
      }
      __syncthreads();   // H1 ready (all layer-1 S reads done)

      // ---- layer 2: C2[i][nb], kc<8 (reads H1 from Q, writes H2 -> P) ----
      {
        floatx4 C2[2][4];
#pragma unroll
        for (int i = 0; i < 2; ++i)
#pragma unroll
          for (int nb = 0; nb < 4; ++nb)
#pragma unroll
            for (int r = 0; r < 4; ++r) C2[i][nb][r] = bs2[i][r];
#pragma unroll
        for (int kc = 0; kc < 8; ++kc) {
          half8 bf[4];
#pragma unroll
          for (int nb = 0; nb < 4; ++nb) {
            half4 lo = *(const half4*)&Q[IDX(kc, nb, 0, l)];
            half4 hi = *(const half4*)&Q[IDX(kc, nb, 1, l)];
            bf[nb] = join(lo, hi);
          }
#pragma unroll
          for (int i = 0; i < 2; ++i)
#pragma unroll
            for (int nb = 0; nb < 4; ++nb)
              C2[i][nb] = MFMA16(WA2[i][kc], bf[nb], C2[i][nb], 0, 0, 0);
        }
#pragma unroll
        for (int i = 0; i < 2; ++i) {
          const int sq = 2*i + qh;
#pragma unroll
          for (int nb = 0; nb < 4; ++nb) {
            half4 v;
#pragma unroll
            for (int r = 0; r < 4; ++r) v[r] = (_Float16)fmaxf(C2[i][nb][r], 0.0f);
            *(half4*)&P[IDX(w, nb, sh, 16*sq + c)] = v;
          }
        }
      }
      __syncthreads();   // H2 ready (all layer-2 H1 reads done)

      // ---- layer 3: C3[nb], kc<8 (reads H2 from P) ----
      floatx4 C3[4];
#pragma unroll
      for (int nb = 0; nb < 4; ++nb)
#pragma unroll
        for (int r = 0; r < 4; ++r) C3[nb][r] = bs3[r];
#pragma unroll
      for (int kc = 0; kc < 8; ++kc) {
        half8 bf[4];
#pragma unroll
        for (int nb = 0; nb < 4; ++nb) {
          half4 lo = *(const half4*)&P[IDX(kc, nb, 0, l)];
          half4 hi = *(const half4*)&P[IDX(kc, nb, 1, l)];
          bf[nb] = join(lo, hi);
        }
#pragma unroll
        for (int nb = 0; nb < 4; ++nb)
          C3[nb] = MFMA16(WA3[kc], bf[nb], C3[nb], 0, 0, 0);
      }

      // ---- RK4 stage update + write next-stage S' -> Q ----
      const float aw = (s4 == 1 || s4 == 2) ? 2.0f : 1.0f;
      const float cs = (s4 == 2) ? h : 0.5f * h;
      const bool first = (s4 == 0), last = (s4 == 3);
      {
        const int sq = 2*(w & 1) + qh;
#pragma unroll
        for (int nb = 0; nb < 4; ++nb) {
          half4 v;
#pragma unroll
          for (int r = 0; r < 4; ++r) {
            float kv = C3[nb][r];
            float an = first ? kv : (ACC[nb][r] + aw * kv);
            ACC[nb][r] = an;
            float yv = Y[nb][r];
            float ynew = yv + (h / 6.0f) * an;
            float yq = last ? ynew : yv;
            Y[nb][r] = yq;
            float sn = last ? yq : (yv + cs * kv);
            v[r] = (_Float16)sn;
          }
          *(half4*)&Q[IDX(w >> 1, nb, sh, 16*sq + c)] = v;
        }
      }
      __syncthreads();   // S' ready (H2 reads done)
    }

    // ---- epilogue: y(1) -> yfin (padded stride, float4), pred = y@Wl+bl --
    // Y[nb][r] covers d = 16w+4q+r: r=0..3 contiguous -> one float4 store.
    // bank(row*132 + d) spreads rows (132 % 32 == 4): conflict-free-ish.
#pragma unroll
    for (int nb = 0; nb < 4; ++nb) {
      float4 v4 = make_float4(Y[nb][0], Y[nb][1], Y[nb][2], Y[nb][3]);
      *(float4*)&sm.yfin[(16*nb + c)*YLD + 16*w + 4*q] = v4;
    }
    __syncthreads();   // yfin ready
    for (int u = tid; u < 640; u += 512) {
      int row = u / 10;
      int o   = u - row * 10;
      float acc = bl[o];
      const float* yr = &sm.yfin[row * YLD];
#pragma unroll
      for (int k4 = 0; k4 < 32; ++k4) {
        float4 y4 = *(const float4*)&yr[4*k4];
        acc = fmaf(y4.x, Wl[(4*k4 + 0)*10 + o], acc);
        acc = fmaf(y4.y, Wl[(4*k4 + 1)*10 + o], acc);
        acc = fmaf(y4.z, Wl[(4*k4 + 2)*10 + o], acc);
        acc = fmaf(y4.w, Wl[(4*k4 + 3)*10 + o], acc);
      }
      out[(R + row)*10 + o] = acc;
    }
    __syncthreads();   // end-of-tile fence: all LDS reads drained before reuse
  }
}

extern "C" void kernel_launch(void* const* d_in, const int* in_sizes, int n_in,
                              void* d_out, int out_size, void* d_ws, size_t ws_size,
                              hipStream_t stream) {
  const float* x  = (const float*)d_in[0];
  const float* W1 = (const float*)d_in[1];
  const float* b1 = (const float*)d_in[2];
  const float* W2 = (const float*)d_in[3];
  const float* b2 = (const float*)d_in[4];
  const float* W3 = (const float*)d_in[5];
  const float* b3 = (const float*)d_in[6];
  const float* Wl = (const float*)d_in[7];
  const float* bl = (const float*)d_in[8];
  float* out = (float*)d_out;

  _Float16* Aw = (_Float16*)d_ws;   // 262144 B

  pack_weights_all<<<512, 256, 0, stream>>>(W1, W2, W3, Aw);
  ode_kernel<<<256, 512, 0, stream>>>(x, b1, b2, b3, Wl, bl, Aw, out);
}

// Round 14
// 170.176 us; speedup vs baseline: 1.3017x; 1.3017x over previous
//
#include <hip/hip_runtime.h>

// ODENet forward, round 14: r12 persistent structure + YLD=132 padded yfin
// (r13's only validated-good piece) + Wl/bl staged in LDS (kills the
// epilogue's per-lane scattered global loads) + r12's scalar epilogue loop
// shape (r13's full-unroll float4 read loop regressed 131->154us despite
// -84% conflicts: conflict cycles were latency-hidden; the real epilogue
// cost is the 128 uncoalesced Wl global loads per output).
// Core (validated): pack kernel + no-spill 128-VGPR weight residency, f16
// MFMA 16x16x32, fp32 state, RK4 N=1 (absmax bit-identical 0.03125 at
// N=8/6/4/3/2/1), lo/hi b64 conflict-free LDS B-fragments, ping-pong 2x32KB,
// grid 256 persistent, 4 row-tiles/WG, weights loaded once.
// HISTORY (do not regress): r5 launch_bounds(512,4) -> weight spill (3.3GB
// HBM); r8 inline f32 gather -> ~50-reg spill; r11 LDS union overlays ->
// post-timing divergence (keep dedicated regions); r13 full-unroll float4
// epilogue reads -> +23us. Keep launch_bounds(512,2).

typedef _Float16 half8 __attribute__((ext_vector_type(8)));
typedef _Float16 half4 __attribute__((ext_vector_type(4)));
typedef float    floatx4 __attribute__((ext_vector_type(4)));

#define MFMA16 __builtin_amdgcn_mfma_f32_16x16x32_f16

constexpr int DDIM  = 118;
constexpr int NSTEP = 1;
constexpr int TILES = 4;      // row-tiles of 64 per WG (grid 256)
constexpr int YLD   = 132;    // yfin row stride (floats): rows spread banks

// B-frag element group offset (f16 units) inside one 32KB half-buffer:
// element(k = 32*kc + 8*(slot>>4) + 4*h + t, n = 16*nb + (slot&15)) at
// IDX(kc,nb,h,slot) + t.
__device__ __forceinline__ int IDX(int kc, int nb, int h, int slot) {
  return (((kc*4 + nb)*2 + h)*64 + slot)*4;
}

struct SMemT {
  _Float16 b[2][16384];   // ping-pong activation buffers, 32KB each
  float raw[7552];        // x staging (dedicated, 30208B)
  float yfin[64 * YLD];   // epilogue 64 x 128 padded to 132 (33792B)
  float wl[1280];         // Wl staged (5120B)
  float bls[10];          // bl staged
};                        // total ~135KB < 160KB/CU (1 WG/CU persistent)

// Fused pack: fp32 W[K][N] (k-major) -> A-fragment order f16 for all 3 mats.
// A1: 16mb x 4kc at out[0..32767]; A2: 16mb x 8kc at +32768; A3: 8mb x 8kc at +98304.
__global__ void pack_weights_all(const float* __restrict__ W1,
                                 const float* __restrict__ W2,
                                 const float* __restrict__ W3,
                                 _Float16* __restrict__ out)
{
  int idx = blockIdx.x * 256 + threadIdx.x;     // 0 .. 131071
  const float* W; int N, kcBits, base;
  if (idx < 32768)        { W = W1; N = 256; kcBits = 2; base = 0;     }
  else if (idx < 98304)   { W = W2; N = 256; kcBits = 3; base = 32768; }
  else                    { W = W3; N = 128; kcBits = 3; base = 98304; }
  int rel = idx - base;
  int j  = rel & 7;
  int L  = (rel >> 3) & 63;
  int blk = rel >> 9;
  int kc = blk & ((1 << kcBits) - 1);
  int mb = blk >> kcBits;
  int k = 32*kc + 8*(L >> 4) + j;
  int m = 16*mb + (L & 15);
  out[idx] = (_Float16)W[k*N + m];
}

__device__ __forceinline__ half8 join(half4 lo, half4 hi) {
  return __builtin_shufflevector(lo, hi, 0, 1, 2, 3, 4, 5, 6, 7);
}

__global__ __launch_bounds__(512, 2)
void ode_kernel(const float* __restrict__ x,
                const float* __restrict__ b1v, const float* __restrict__ b2v,
                const float* __restrict__ b3v,
                const float* __restrict__ Wl,  const float* __restrict__ bl,
                const _Float16* __restrict__ Aw, float* __restrict__ out)
{
  __shared__ SMemT sm;
  const int tid = threadIdx.x;
  const int w   = tid >> 6;    // wave 0..7
  const int l   = tid & 63;
  const int q   = l >> 4;
  const int c   = l & 15;

  const int sh  = q & 1;       // store-side h
  const int qh  = q >> 1;

  // ---- stage Wl/bl into LDS (once per WG, coalesced) ----
  for (int i = tid; i < 1280; i += 512) sm.wl[i] = Wl[i];
  if (tid < 10) sm.bls[tid] = bl[tid];

  // ---- weight A-fragments -> registers (ONCE per WG): 128 VGPRs/wave ----
  const _Float16* A1 = Aw;           // 16 mb x 4 kc
  const _Float16* A2 = Aw + 32768;   // 16 mb x 8 kc
  const _Float16* A3 = Aw + 98304;   //  8 mb x 8 kc
  half8 WA1[2][4], WA2[2][8], WA3[8];
#pragma unroll
  for (int i = 0; i < 2; ++i)
#pragma unroll
    for (int kc = 0; kc < 4; ++kc)
      WA1[i][kc] = *(const half8*)&A1[((((2*w+i)*4 + kc)*64) + l)*8];
#pragma unroll
  for (int i = 0; i < 2; ++i)
#pragma unroll
    for (int kc = 0; kc < 8; ++kc)
      WA2[i][kc] = *(const half8*)&A2[((((2*w+i)*8 + kc)*64) + l)*8];
#pragma unroll
  for (int kc = 0; kc < 8; ++kc)
    WA3[kc] = *(const half8*)&A3[(((w*8 + kc)*64) + l)*8];

  // ---- biases (per-lane; m = 16*mb + 4q + r), once per WG ----
  float bs1[2][4], bs2[2][4], bs3[4];
#pragma unroll
  for (int i = 0; i < 2; ++i)
#pragma unroll
    for (int r = 0; r < 4; ++r) {
      bs1[i][r] = b1v[16*(2*w+i) + 4*q + r];
      bs2[i][r] = b2v[16*(2*w+i) + 4*q + r];
    }
#pragma unroll
  for (int r = 0; r < 4; ++r) bs3[r] = b3v[16*w + 4*q + r];

  const float h = 1.0f / (float)NSTEP;

#pragma unroll 1
  for (int t = 0; t < TILES; ++t) {
    const int R = blockIdx.x * (64 * TILES) + t * 64;

    // ---- stage this tile's x block into dedicated raw ----
    const float* xblk = x + (size_t)R * DDIM;
    for (int i = tid; i < 1888; i += 512)
      *(float4*)&sm.raw[i*4] = *(const float4*)&xblk[i*4];
    __syncthreads();   // raw ready (also fences wl/bl staging on t==0)

    // ---- build initial S in b[0] (lo/hi B-frag layout, zero-pad k>=118) --
    for (int g = tid; g < 2048; g += 512) {
      int slot = g & 63;
      int hh   = (g >> 6) & 1;
      int nb   = (g >> 7) & 3;
      int kc   = g >> 9;
      int n  = 16*nb + (slot & 15);
      int k0 = 32*kc + 8*(slot >> 4) + 4*hh;
      half4 v;
#pragma unroll
      for (int tt = 0; tt < 4; ++tt) {
        int k = k0 + tt;
        v[tt] = (_Float16)((k < DDIM) ? sm.raw[n*DDIM + k] : 0.0f);
      }
      *(half4*)&sm.b[0][IDX(kc, nb, hh, slot)] = v;
    }

    // ---- Y init (fp32): d = 16w + 4q + r, n = 16nb + c ----
    float Y[4][4], ACC[4][4];
#pragma unroll
    for (int nb = 0; nb < 4; ++nb)
#pragma unroll
      for (int r = 0; r < 4; ++r) {
        int d = 16*w + 4*q + r;
        int n = 16*nb + c;
        Y[nb][r]  = (d < DDIM) ? sm.raw[n*DDIM + d] : 0.0f;
        ACC[nb][r] = 0.0f;
      }
    __syncthreads();   // S ready

#pragma unroll 1
    for (int it = 0; it < 4*NSTEP; ++it) {
      const int s4 = it & 3;
      _Float16* P = sm.b[it & 1];         // holds S, receives H2
      _Float16* Q = sm.b[(it & 1) ^ 1];   // receives H1, then S'

      // ---- layer 1: C1[i][nb], kc<4 (reads S from P) ----
      {
        floatx4 C1[2][4];
#pragma unroll
        for (int i = 0; i < 2; ++i)
#pragma unroll
          for (int nb = 0; nb < 4; ++nb)
#pragma unroll
            for (int r = 0; r < 4; ++r) C1[i][nb][r] = bs1[i][r];
#pragma unroll
        for (int kc = 0; kc < 4; ++kc) {
          half8 bf[4];
#pragma unroll
          for (int nb = 0; nb < 4; ++nb) {
            half4 lo = *(const half4*)&P[IDX(kc, nb, 0, l)];
            half4 hi = *(const half4*)&P[IDX(kc, nb, 1, l)];
            bf[nb] = join(lo, hi);
          }
#pragma unroll
          for (int i = 0; i < 2; ++i)
#pragma unroll
            for (int nb = 0; nb < 4; ++nb)
              C1[i][nb] = MFMA16(WA1[i][kc], bf[nb], C1[i][nb], 0, 0, 0);
        }
        // store H1 -> Q: mb = 2w+i -> kc_t = w, sq = 2i + qh, h = sh
#pragma unroll
        for (int i = 0; i < 2; ++i) {
          const int sq = 2*i + qh;
#pragma unroll
          for (int nb = 0; nb < 4; ++nb) {
            half4 v;
#pragma unroll
            for (int r = 0; r < 4; ++r) v[r] = (_Float16)fmaxf(C1[i][nb][r], 0.0f);
            *(half4*)&Q[IDX(w, nb, sh, 16*sq + c)] = v;
          }
        }
      }
      __syncthreads();   // H1 ready (all layer-1 S reads done)

      // ---- layer 2: C2[i][nb], kc<8 (reads H1 from Q, writes H2 -> P) ----
      {
        floatx4 C2[2][4];
#pragma unroll
        for (int i = 0; i < 2; ++i)
#pragma unroll
          for (int nb = 0; nb < 4; ++nb)
#pragma unroll
            for (int r = 0; r < 4; ++r) C2[i][nb][r] = bs2[i][r];
#pragma unroll
        for (int kc = 0; kc < 8; ++kc) {
          half8 bf[4];
#pragma unroll
          for (int nb = 0; nb < 4; ++nb) {
            half4 lo = *(const half4*)&Q[IDX(kc, nb, 0, l)];
            half4 hi = *(const half4*)&Q[IDX(kc, nb, 1, l)];
            bf[nb] = join(lo, hi);
          }
#pragma unroll
          for (int i = 0; i < 2; ++i)
#pragma unroll
            for (int nb = 0; nb < 4; ++nb)
              C2[i][nb] = MFMA16(WA2[i][kc], bf[nb], C2[i][nb], 0, 0, 0);
        }
#pragma unroll
        for (int i = 0; i < 2; ++i) {
          const int sq = 2*i + qh;
#pragma unroll
          for (int nb = 0; nb < 4; ++nb) {
            half4 v;
#pragma unroll
            for (int r = 0; r < 4; ++r) v[r] = (_Float16)fmaxf(C2[i][nb][r], 0.0f);
            *(half4*)&P[IDX(w, nb, sh, 16*sq + c)] = v;
          }
        }
      }
      __syncthreads();   // H2 ready (all layer-2 H1 reads done)

      // ---- layer 3: C3[nb], kc<8 (reads H2 from P) ----
      floatx4 C3[4];
#pragma unroll
      for (int nb = 0; nb < 4; ++nb)
#pragma unroll
        for (int r = 0; r < 4; ++r) C3[nb][r] = bs3[r];
#pragma unroll
      for (int kc = 0; kc < 8; ++kc) {
        half8 bf[4];
#pragma unroll
        for (int nb = 0; nb < 4; ++nb) {
          half4 lo = *(const half4*)&P[IDX(kc, nb, 0, l)];
          half4 hi = *(const half4*)&P[IDX(kc, nb, 1, l)];
          bf[nb] = join(lo, hi);
        }
#pragma unroll
        for (int nb = 0; nb < 4; ++nb)
          C3[nb] = MFMA16(WA3[kc], bf[nb], C3[nb], 0, 0, 0);
      }

      // ---- RK4 stage update + write next-stage S' -> Q ----
      const float aw = (s4 == 1 || s4 == 2) ? 2.0f : 1.0f;
      const float cs = (s4 == 2) ? h : 0.5f * h;
      const bool first = (s4 == 0), last = (s4 == 3);
      {
        const int sq = 2*(w & 1) + qh;
#pragma unroll
        for (int nb = 0; nb < 4; ++nb) {
          half4 v;
#pragma unroll
          for (int r = 0; r < 4; ++r) {
            float kv = C3[nb][r];
            float an = first ? kv : (ACC[nb][r] + aw * kv);
            ACC[nb][r] = an;
            float yv = Y[nb][r];
            float ynew = yv + (h / 6.0f) * an;
            float yq = last ? ynew : yv;
            Y[nb][r] = yq;
            float sn = last ? yq : (yv + cs * kv);
            v[r] = (_Float16)sn;
          }
          *(half4*)&Q[IDX(w >> 1, nb, sh, 16*sq + c)] = v;
        }
      }
      __syncthreads();   // S' ready (H2 reads done)
    }

    // ---- epilogue: y(1) -> yfin (padded stride, float4 stores), then
    //      pred = y @ Wl + bl, all operands from LDS ----
#pragma unroll
    for (int nb = 0; nb < 4; ++nb) {
      float4 v4 = make_float4(Y[nb][0], Y[nb][1], Y[nb][2], Y[nb][3]);
      *(float4*)&sm.yfin[(16*nb + c)*YLD + 16*w + 4*q] = v4;
    }
    __syncthreads();   // yfin ready
    for (int u = tid; u < 640; u += 512) {
      int row = u / 10;
      int o   = u - row * 10;
      float acc = sm.bls[o];
      const float* yr = &sm.yfin[row * YLD];
#pragma unroll 8
      for (int k = 0; k < 128; ++k)
        acc = fmaf(yr[k], sm.wl[k*10 + o], acc);
      out[(R + row)*10 + o] = acc;
    }
    __syncthreads();   // end-of-tile fence: all LDS reads drained before reuse
  }
}

extern "C" void kernel_launch(void* const* d_in, const int* in_sizes, int n_in,
                              void* d_out, int out_size, void* d_ws, size_t ws_size,
                              hipStream_t stream) {
  const float* x  = (const float*)d_in[0];
  const float* W1 = (const float*)d_in[1];
  const float* b1 = (const float*)d_in[2];
  const float* W2 = (const float*)d_in[3];
  const float* b2 = (const float*)d_in[4];
  const float* W3 = (const float*)d_in[5];
  const float* b3 = (const float*)d_in[6];
  const float* Wl = (const float*)d_in[7];
  const float* bl = (const float*)d_in[8];
  float* out = (float*)d_out;

  _Float16* Aw = (_Float16*)d_ws;   // 262144 B

  pack_weights_all<<<512, 256, 0, stream>>>(W1, W2, W3, Aw);
  ode_kernel<<<256, 512, 0, stream>>>(x, b1, b2, b3, Wl, bl, Aw, out);
}